// Round 3
// baseline (940.495 us; speedup 1.0000x reference)
//
#include <hip/hip_runtime.h>
#include <hip/hip_bf16.h>
#include <math.h>

// Problem constants
#define B_    16
#define D_    256
#define T_    2048
#define K_    1024
#define BT_   (B_ * T_)            // 32768 rows
#define BDT_  (B_ * D_ * T_)       // 8388608 elements
#define MUSIC_W 0.1f
#define EPS_COS 1e-8f
#define MARGIN_TAU 3e-4f           // > 4x the 2*ulp(256) np-f32 comparison discrepancy

// ---------------------------------------------------------------------------
// numpy pairwise sum-of-squares (exact replication of numpy's pairwise_sum
// for n=128 / n=256): 8 accumulators, sequential strided adds, fixed combine
// tree. __fmul_rn/__fadd_rn prevent FMA contraction / reassociation.
// ---------------------------------------------------------------------------
__device__ __forceinline__ float pw128_sq(const float* a, int stride) {
    float r[8];
    #pragma unroll
    for (int j = 0; j < 8; ++j) { float v = a[j * stride]; r[j] = __fmul_rn(v, v); }
    for (int i = 8; i < 128; i += 8) {
        #pragma unroll
        for (int j = 0; j < 8; ++j) {
            float v = a[(i + j) * stride];
            r[j] = __fadd_rn(r[j], __fmul_rn(v, v));
        }
    }
    return __fadd_rn(__fadd_rn(__fadd_rn(r[0], r[1]), __fadd_rn(r[2], r[3])),
                     __fadd_rn(__fadd_rn(r[4], r[5]), __fadd_rn(r[6], r[7])));
}
__device__ __forceinline__ float pw256_sq(const float* a, int stride) {
    return __fadd_rn(pw128_sq(a, stride), pw128_sq(a + 128 * stride, stride));
}

// ---------------------------------------------------------------------------
// Kernel 1: transpose codebook to ct[d][k]; zero counts + double sums.
// ---------------------------------------------------------------------------
__global__ __launch_bounds__(256) void prep_trans(const float* __restrict__ cb,
                                                  float* __restrict__ ct,
                                                  float* __restrict__ counts,
                                                  double* __restrict__ sums) {
    int k = blockIdx.x;        // 0..1023
    int d = threadIdx.x;       // 0..255
    ct[d * K_ + k] = cb[k * D_ + d];
    if (d == 0) counts[k] = 0.0f;
    if (k == 0 && d < 2) sums[d] = 0.0;
}

// ---------------------------------------------------------------------------
// Kernel 2: cc[k] = np-pairwise-f32 sum of codebook row squares.
// ---------------------------------------------------------------------------
__global__ __launch_bounds__(256) void prep_cc(const float* __restrict__ cb,
                                               float* __restrict__ c2) {
    int k = blockIdx.x * 256 + threadIdx.x;   // 0..1023
    if (k < K_) c2[k] = pw256_sq(cb + (size_t)k * D_, 1);
}

// ---------------------------------------------------------------------------
// Kernel 3: xx[row] = np-pairwise-f32 sum of x_flat row squares.
// x layout [B][D][T]; x_flat row (b,t) element d = x[b*D*T + d*T + t].
// ---------------------------------------------------------------------------
__global__ __launch_bounds__(256) void xx_kernel(const float* __restrict__ x,
                                                 float* __restrict__ xx) {
    int row = blockIdx.x * 256 + threadIdx.x;  // 0..32767
    int b = row >> 11, t = row & 2047;
    xx[row] = pw256_sq(x + (size_t)b * (D_ * T_) + t, T_);
}

// ---------------------------------------------------------------------------
// Kernel 4: argmin with np-f32 replication semantics.
// Fast path: s = cc[k] - 2*dot (f32 register tile); if top-2 margin >= TAU the
// winner is provably the np winner. Else: full np replication for the row —
// M = f32(round(f64 dot)), s = fl(fl(xx - fl(2M)) + cc), first-index argmin.
// ---------------------------------------------------------------------------
#define XSTR 260   // padded LDS row stride (floats); multiple of 4 -> 16B aligned

__global__ __launch_bounds__(256) void argmin_kernel(const float* __restrict__ x,
                                                     const float* __restrict__ ct,
                                                     const float* __restrict__ c2,
                                                     const float* __restrict__ xx,
                                                     int* __restrict__ codes,
                                                     float* __restrict__ codes_f) {
    __shared__ __align__(16) float xs[32 * XSTR];
    int blk = blockIdx.x;            // 0..1023
    int row0 = blk * 32;
    int b = row0 >> 11;              // T=2048
    int t0 = row0 & 2047;
    const float* xb = x + (size_t)b * (D_ * T_);

    int tid = threadIdx.x;
    int li = tid & 31;               // row within tile
    int dhi = tid >> 5;              // 0..7
    #pragma unroll 4
    for (int p = 0; p < 32; ++p) {
        int d = p * 8 + dhi;
        xs[li * XSTR + d] = xb[d * T_ + t0 + li];
    }
    __syncthreads();

    int wave = tid >> 6;
    int lane = tid & 63;
    int rbase = wave * 8;

    float best[8], sec[8];
    int bestk[8];
    #pragma unroll
    for (int r = 0; r < 8; ++r) { best[r] = 3.4e38f; sec[r] = 3.4e38f; bestk[r] = 0; }

    for (int kg = 0; kg < 2; ++kg) {
        int kbase = kg * 512 + lane;
        float acc[8][8];
        #pragma unroll
        for (int r = 0; r < 8; ++r)
            #pragma unroll
            for (int j = 0; j < 8; ++j) acc[r][j] = 0.0f;

        for (int d = 0; d < 256; d += 4) {
            float cv[4][8];
            #pragma unroll
            for (int dd = 0; dd < 4; ++dd) {
                const float* ctp = ct + (size_t)(d + dd) * K_ + kbase;
                #pragma unroll
                for (int j = 0; j < 8; ++j) cv[dd][j] = ctp[j * 64];
            }
            #pragma unroll
            for (int r = 0; r < 8; ++r) {
                float4 xv = *(const float4*)&xs[(rbase + r) * XSTR + d];
                #pragma unroll
                for (int j = 0; j < 8; ++j) {
                    float a = acc[r][j];
                    a = fmaf(xv.x, cv[0][j], a);
                    a = fmaf(xv.y, cv[1][j], a);
                    a = fmaf(xv.z, cv[2][j], a);
                    a = fmaf(xv.w, cv[3][j], a);
                    acc[r][j] = a;
                }
            }
        }

        #pragma unroll
        for (int j = 0; j < 8; ++j) {
            int k = kg * 512 + j * 64 + lane;
            float c2k = c2[k];
            #pragma unroll
            for (int r = 0; r < 8; ++r) {
                float s = c2k - 2.0f * acc[r][j];
                if (s < best[r]) { sec[r] = best[r]; best[r] = s; bestk[r] = k; }
                else if (s < sec[r]) { sec[r] = s; }
            }
        }
    }

    // cross-lane top-2 reduce (best tie -> smallest k)
    #pragma unroll
    for (int r = 0; r < 8; ++r) {
        float v = best[r], s2 = sec[r];
        int ki = bestk[r];
        #pragma unroll
        for (int off = 32; off; off >>= 1) {
            float ov = __shfl_xor(v, off, 64);
            int ok = __shfl_xor(ki, off, 64);
            float os = __shfl_xor(s2, off, 64);
            float nb = fminf(v, ov);
            float ns = fminf(fmaxf(v, ov), fminf(s2, os));
            if (ov < v || (ov == v && ok < ki)) ki = ok;
            v = nb; s2 = ns;
        }
        int row = row0 + rbase + r;

        if (s2 - v < MARGIN_TAU) {
            // ---- np-f32 replication for this row (wave-cooperative) ----
            const float* xr = &xs[(rbase + r) * XSTR];
            float xxv = xx[row];
            double dacc[16];
            #pragma unroll
            for (int kk = 0; kk < 16; ++kk) dacc[kk] = 0.0;
            for (int d = 0; d < 256; ++d) {
                double xv = (double)xr[d];
                const float* ctd = ct + (size_t)d * K_ + lane;
                #pragma unroll
                for (int kk = 0; kk < 16; ++kk)
                    dacc[kk] = fma(xv, (double)ctd[kk * 64], dacc[kk]);
            }
            float bv = 3.4e38f;
            int bk = 0;
            #pragma unroll
            for (int kk = 0; kk < 16; ++kk) {
                int k = kk * 64 + lane;
                float M = (float)dacc[kk];                       // correctly-rounded f32 dot
                float s = __fadd_rn(__fsub_rn(xxv, __fmul_rn(2.0f, M)), c2[k]);
                if (s < bv) { bv = s; bk = k; }                  // kk ascending -> first index
            }
            #pragma unroll
            for (int off = 32; off; off >>= 1) {
                float ov = __shfl_xor(bv, off, 64);
                int ok = __shfl_xor(bk, off, 64);
                if (ov < bv || (ov == bv && ok < bk)) { bv = ov; bk = ok; }
            }
            ki = bk;
        }
        if (lane == 0) { codes[row] = ki; codes_f[row] = (float)ki; }
    }
}

// ---------------------------------------------------------------------------
// Kernel 5: music_sim — cosine similarity between projected x and context.
// ---------------------------------------------------------------------------
__global__ __launch_bounds__(256) void music_kernel(const float* __restrict__ x,
                                                    const float* __restrict__ mc,
                                                    const float* __restrict__ w,
                                                    const float* __restrict__ bp,
                                                    float* __restrict__ sim) {
    __shared__ float wsm[3 * 256];
    __shared__ float bs[3];
    int tid = threadIdx.x;
    for (int i = tid; i < 768; i += 256) wsm[i] = w[i];
    if (tid < 3) bs[tid] = bp[tid];
    __syncthreads();

    int row = blockIdx.x * 256 + tid;   // 0..32767
    int b = row >> 11, t = row & 2047;
    const float* xp = x + (size_t)b * (D_ * T_) + t;
    float m0 = bs[0], m1 = bs[1], m2 = bs[2];
    #pragma unroll 8
    for (int d = 0; d < 256; ++d) {
        float xv = xp[d * T_];
        m0 = fmaf(wsm[d], xv, m0);
        m1 = fmaf(wsm[256 + d], xv, m1);
        m2 = fmaf(wsm[512 + d], xv, m2);
    }
    const float* mcp = mc + (size_t)b * (3 * T_) + t;
    float c0 = mcp[0], c1 = mcp[T_], c2v = mcp[2 * T_];
    float num = m0 * c0 + m1 * c1 + m2 * c2v;
    float npn = fmaxf(sqrtf(m0 * m0 + m1 * m1 + m2 * m2), EPS_COS);
    float ncn = fmaxf(sqrtf(c0 * c0 + c1 * c1 + c2v * c2v), EPS_COS);
    sim[row] = num / (npn * ncn);
}

// ---------------------------------------------------------------------------
// Kernel 6: histogram of codes
// ---------------------------------------------------------------------------
__global__ __launch_bounds__(256) void hist_kernel(const int* __restrict__ codes,
                                                   float* __restrict__ counts) {
    int row = blockIdx.x * 256 + threadIdx.x;
    if (row < BT_) atomicAdd(&counts[codes[row]], 1.0f);
}

// ---------------------------------------------------------------------------
// Kernel 7: quantized output (= straight-through value) + sum of (q-x)^2
// ---------------------------------------------------------------------------
__global__ __launch_bounds__(256) void quant_kernel(const float* __restrict__ x,
                                                    const float* __restrict__ cb,
                                                    const int* __restrict__ codes,
                                                    float* __restrict__ out0,
                                                    double* __restrict__ sums) {
    int n = blockIdx.x * 256 + threadIdx.x;     // < 8388608
    int b = n >> 19;                            // D*T = 2^19
    int rem = n & (524288 - 1);
    int d = rem >> 11;
    int t = rem & 2047;
    int code = codes[b * T_ + t];
    float q = cb[code * D_ + d];
    out0[n] = q;
    float diff = q - x[n];
    float sq = diff * diff;
    #pragma unroll
    for (int off = 32; off; off >>= 1) sq += __shfl_down(sq, off, 64);
    __shared__ float part[4];
    int lane = threadIdx.x & 63, wv = threadIdx.x >> 6;
    if (lane == 0) part[wv] = sq;
    __syncthreads();
    if (threadIdx.x == 0) {
        double s = (double)part[0] + part[1] + part[2] + part[3];
        atomicAdd(&sums[0], s);
    }
}

// ---------------------------------------------------------------------------
// Kernel 8: music loss sum
// ---------------------------------------------------------------------------
__global__ __launch_bounds__(256) void mloss_kernel(const float* __restrict__ sim,
                                                    const int* __restrict__ codes,
                                                    double* __restrict__ sums) {
    int idx = blockIdx.x * 256 + threadIdx.x;   // < 16*2047
    float val = 0.0f;
    if (idx < B_ * (T_ - 1)) {
        int b = idx / (T_ - 1);
        int t = idx - b * (T_ - 1);
        int base = b * T_ + t;
        if (codes[base + 1] != codes[base])
            val = fabsf(sim[base + 1] - sim[base]);
    }
    #pragma unroll
    for (int off = 32; off; off >>= 1) val += __shfl_down(val, off, 64);
    __shared__ float part[4];
    int lane = threadIdx.x & 63, wv = threadIdx.x >> 6;
    if (lane == 0) part[wv] = val;
    __syncthreads();
    if (threadIdx.x == 0) {
        double s = (double)part[0] + part[1] + part[2] + part[3];
        atomicAdd(&sums[1], s);
    }
}

// ---------------------------------------------------------------------------
// Kernel 9: finalize — perplexity + scalar outputs. Single block.
// ---------------------------------------------------------------------------
__global__ __launch_bounds__(256) void final_kernel(const float* __restrict__ counts,
                                                    const double* __restrict__ sums,
                                                    float* __restrict__ outS) {
    int tid = threadIdx.x;
    float e = 0.0f;
    for (int k = tid; k < K_; k += 256) {
        float p = counts[k] * (1.0f / (float)BT_);
        e += p * logf(p + 1e-10f);
    }
    #pragma unroll
    for (int off = 32; off; off >>= 1) e += __shfl_down(e, off, 64);
    __shared__ float part[4];
    int lane = tid & 63, wv = tid >> 6;
    if (lane == 0) part[wv] = e;
    __syncthreads();
    if (tid == 0) {
        float etot = part[0] + part[1] + part[2] + part[3];
        float perp = expf(-etot);
        float commitment = (float)(sums[0] / (double)BDT_);
        float ml = (float)(sums[1] / (double)(B_ * (T_ - 1)));
        outS[0] = commitment + MUSIC_W * ml;   // commitment_total
        outS[1] = commitment;                  // codebook_loss (same forward value)
        outS[2] = perp;                        // perplexity
        outS[3] = ml;                          // music_loss
    }
}

// ---------------------------------------------------------------------------
extern "C" void kernel_launch(void* const* d_in, const int* in_sizes, int n_in,
                              void* d_out, int out_size, void* d_ws, size_t ws_size,
                              hipStream_t stream) {
    const float* x   = (const float*)d_in[0];   // [16,256,2048]
    const float* mc  = (const float*)d_in[1];   // [16,3,2048]
    const float* cb  = (const float*)d_in[2];   // [1024,256]
    const float* wp  = (const float*)d_in[3];   // [3,256]
    const float* bp  = (const float*)d_in[4];   // [3]

    // workspace layout
    float* ct     = (float*)d_ws;           // 262144 f32 (codebook^T [d][k])
    float* c2     = ct + (D_ * K_);         // 1024 (np-pairwise |c|^2)
    float* xx     = c2 + K_;                // 32768 (np-pairwise |x|^2 per row)
    float* sim    = xx + BT_;               // 32768
    float* counts = sim + BT_;              // 1024
    int*   codes  = (int*)(counts + K_);    // 32768
    double* sums  = (double*)(codes + BT_); // 2 doubles

    // output layout (all f32, concatenated flat in reference return order)
    float* out0    = (float*)d_out;         // quantized_st [16,256,2048]
    float* codes_f = out0 + BDT_;           // codes [16,2048] as float
    float* outS    = codes_f + BT_;         // 4 scalars

    prep_trans<<<K_, 256, 0, stream>>>(cb, ct, counts, sums);
    prep_cc<<<4, 256, 0, stream>>>(cb, c2);
    xx_kernel<<<BT_ / 256, 256, 0, stream>>>(x, xx);
    argmin_kernel<<<BT_ / 32, 256, 0, stream>>>(x, ct, c2, xx, codes, codes_f);
    music_kernel<<<BT_ / 256, 256, 0, stream>>>(x, mc, wp, bp, sim);
    hist_kernel<<<BT_ / 256, 256, 0, stream>>>(codes, counts);
    quant_kernel<<<BDT_ / 256, 256, 0, stream>>>(x, cb, codes, out0, sums);
    mloss_kernel<<<(B_ * (T_ - 1) + 255) / 256, 256, 0, stream>>>(sim, codes, sums);
    final_kernel<<<1, 256, 0, stream>>>(counts, sums, outS);
}